// Round 6
// baseline (4381.877 us; speedup 1.0000x reference)
//
#include <hip/hip_runtime.h>
#include <hip/hip_bf16.h>

#define DEVINL __device__ __forceinline__

typedef __attribute__((ext_vector_type(8))) short s8v;    // 8 x bf16 bits
typedef __attribute__((ext_vector_type(16))) float f16v;  // 32x32 MFMA accum

using bf16 = __hip_bfloat16;
typedef unsigned short u16;

DEVINL u16 f2bu(float f) {
  bf16 h = __float2bfloat16(f);  // RNE
  return *reinterpret_cast<u16*>(&h);
}

DEVINL void gload16(const void* g, void* l) {
  // async global->LDS, 16B/lane; LDS dest = wave-uniform base + lane*16
  __builtin_amdgcn_global_load_lds((const __attribute__((address_space(1))) void*)g,
                                   (__attribute__((address_space(3))) void*)l, 16, 0, 0);
}

#define BAR()    __builtin_amdgcn_s_barrier()
#define LGKM(n)  asm volatile("s_waitcnt lgkmcnt(" #n ")" ::: "memory")
#define VM(n)    asm volatile("s_waitcnt vmcnt(" #n ")" ::: "memory")
#define SCHED0() __builtin_amdgcn_sched_barrier(0)

// ---------------- conversion kernels ----------------
__global__ void k_f32_to_bf16(const float* __restrict__ x, u16* __restrict__ y, long n4) {
  long i = (long)blockIdx.x * blockDim.x + threadIdx.x;
  if (i >= n4) return;
  float4 v = ((const float4*)x)[i];
  ushort4 o;
  o.x = f2bu(v.x); o.y = f2bu(v.y); o.z = f2bu(v.z); o.w = f2bu(v.w);
  ((ushort4*)y)[i] = o;
}

// W [rows][cols] fp32 -> Wt [cols][rows] bf16
__global__ void k_transpose_bf16(const float* __restrict__ W, u16* __restrict__ Wt,
                                 int rows, int cols) {
  __shared__ float tile[32][33];
  const int tx = threadIdx.x, ty = threadIdx.y;
  const int c0 = blockIdx.x * 32, r0 = blockIdx.y * 32;
  #pragma unroll
  for (int i = ty; i < 32; i += 8)
    tile[i][tx] = W[(long)(r0 + i) * cols + (c0 + tx)];
  __syncthreads();
  #pragma unroll
  for (int i = ty; i < 32; i += 8)
    Wt[(long)(c0 + i) * rows + (r0 + tx)] = f2bu(tile[tx][i]);
}

// ---------------- 256x256 GEMM: A-only-LDS ring + B-direct-global ------------
// 8 waves (2M x 4N), per-wave 128x64 = 4x2 tiles of 32x32, mfma_f32_32x32x16.
// LDS = 4-tile A ring (4 x 32KB = 128KB), staged 2 tiles ahead, 1 gload/phase.
// A-swizzle: stored chunk c holds global k-chunk c ^ (row&7) (bank-balanced).
// B fragments load global->VGPR directly (L2-hot weights), 1 phase ahead.
// Per phase (= K-sub of 16): VM(9);BAR; 4 ds_read (a_next); 2 B-loads (b_next);
// 1 stage gload; LGKM(4);sched_barrier; 8 MFMA.  Constant 3 vm-ops/phase
// (tail-clamped) makes VM(9) an exact 4-phase-old drain.
// EPI=1: C = bf16(relu(acc+bias[col]));  EPI=2: oacc[row] += sum relu(..)*w3
extern __shared__ char smem[];

template<int EPI>
__global__ __launch_bounds__(512, 2)
void k_gemm8(const u16* __restrict__ A, const u16* __restrict__ Bt,
             u16* __restrict__ C, const float* __restrict__ bias,
             const float* __restrict__ w3, float* __restrict__ oacc,
             int N, int K) {
  const int tid = threadIdx.x;
  const int w = tid >> 6, lane = tid & 63;
  // XCD-aware bijective swizzle (gridDim.x % 8 == 0: 2048 blocks)
  const int id = blockIdx.x;
  const int cpx = gridDim.x >> 3;
  const int sw = (id & 7) * cpx + (id >> 3);
  const int bn = sw & 7, bm = sw >> 3;          // N/256 == 8 for all our calls
  const int wm = (w >> 2) * 128, wn = (w & 3) * 64;
  const int nt = K >> 6;

  f16v acc[4][2];
  #pragma unroll
  for (int mi = 0; mi < 4; ++mi)
    #pragma unroll
    for (int ni = 0; ni < 2; ++ni)
      #pragma unroll
      for (int r = 0; r < 16; ++r) acc[mi][ni][r] = 0.f;

  // A-stage source (per-lane, pre-swizzled chunk): round j stages rows
  // j*64 + w*8 + (lane>>3), stored chunk (lane&7) holds global chunk
  // (lane&7)^((lane>>3)&7)  [row&7 == (lane>>3)&7].
  const u16* gAs = A + ((long)(bm * 256 + w * 8 + (lane >> 3))) * K
                     + ((lane & 7) ^ ((lane >> 3) & 7)) * 8;
  // B direct-load base: col = lane&31 (+ni*32), k-half = (lane>>5)*8
  const u16* gBs = Bt + ((long)(bn * 256 + wn + (lane & 31))) * K + ((lane >> 5) & 1) * 8;
  // A ds_read base parts: row = wm + mi*32 + (lane&31); phys chunk =
  // (2*ks | b5) ^ (lane&7)  ->  kx = (ks<<5) ^ apl16
  const uint a_row = (uint)(wm + (lane & 31)) * 128u;
  const uint apl16 = ((uint)(((lane >> 5) & 1) ^ (lane & 7))) << 4;

#define STAGE1(bufidx, j, tt) \
  gload16(gAs + (long)(j) * 64 * K + (long)(tt) * 64, \
          smem + (uint)(bufidx) * 32768u + (uint)((j) * 8 + w) * 1024u)
#define RDA(dst, bufidx, ks) do { \
    const uint base_ = (uint)(bufidx) * 32768u + a_row + (((uint)(ks) << 5) ^ apl16); \
    dst[0] = *(const s8v*)(smem + base_); \
    dst[1] = *(const s8v*)(smem + base_ + 4096u); \
    dst[2] = *(const s8v*)(smem + base_ + 8192u); \
    dst[3] = *(const s8v*)(smem + base_ + 12288u); } while (0)
#define RDB(dst, kk) do { \
    dst[0] = *(const s8v*)(gBs + (kk)); \
    dst[1] = *(const s8v*)(gBs + (long)32 * K + (kk)); } while (0)
#define MFMA8(Aa, Bb) do { \
    __builtin_amdgcn_s_setprio(1); \
    _Pragma("unroll") \
    for (int mi_ = 0; mi_ < 4; ++mi_) { \
      acc[mi_][0] = __builtin_amdgcn_mfma_f32_32x32x16_bf16(Aa[mi_], Bb[0], acc[mi_][0], 0, 0, 0); \
      acc[mi_][1] = __builtin_amdgcn_mfma_f32_32x32x16_bf16(Aa[mi_], Bb[1], acc[mi_][1], 0, 0, 0); } \
    __builtin_amdgcn_s_setprio(0); } while (0)

  s8v aA[4], aB[4], bA[2], bB[2];

  // ---- prologue: stage tiles 0,1 (clamped); drain t0; first frags ----
  {
    const int t1 = (nt > 1) ? 1 : 0;
    STAGE1(0, 0, 0); STAGE1(0, 1, 0); STAGE1(0, 2, 0); STAGE1(0, 3, 0);
    STAGE1(1, 0, t1); STAGE1(1, 1, t1); STAGE1(1, 2, t1); STAGE1(1, 3, t1);
  }
  VM(4); BAR();
  RDA(aA, 0, 0);
  RDB(bA, 0);
  int kn = 16;
  const int kcap = K - 16;

  for (int t = 0; t < nt; ++t) {
    const int bc = t & 3, bnx = (t + 1) & 3, bs = (t + 2) & 3;
    const int tt = (t + 2 < nt) ? (t + 2) : (nt - 1);
    int knc;
    // ---- PH0: compute k-sub0 (aA,bA); prefetch k-sub1 ----
    VM(9); BAR();
    RDA(aB, bc, 1);
    knc = kn < kcap ? kn : kcap; RDB(bB, knc); kn += 16;
    STAGE1(bs, 0, tt);
    LGKM(4); SCHED0();
    MFMA8(aA, bA);
    // ---- PH1: k-sub1; prefetch k-sub2 ----
    VM(9); BAR();
    RDA(aA, bc, 2);
    knc = kn < kcap ? kn : kcap; RDB(bA, knc); kn += 16;
    STAGE1(bs, 1, tt);
    LGKM(4); SCHED0();
    MFMA8(aB, bB);
    // ---- PH2: k-sub2; prefetch k-sub3 ----
    VM(9); BAR();
    RDA(aB, bc, 3);
    knc = kn < kcap ? kn : kcap; RDB(bB, knc); kn += 16;
    STAGE1(bs, 2, tt);
    LGKM(4); SCHED0();
    MFMA8(aA, bA);
    // ---- PH3: k-sub3; prefetch next tile k-sub0 ----
    VM(9); BAR();
    RDA(aA, bnx, 0);
    knc = kn < kcap ? kn : kcap; RDB(bA, knc); kn += 16;
    STAGE1(bs, 3, tt);
    LGKM(4); SCHED0();
    MFMA8(aB, bB);
  }

  // ---- epilogue (32x32 C/D: col = lane&31, row = (r&3)+8*(r>>2)+4*(lane>>5)) ----
  const int colb = bn * 256 + wn + (lane & 31);
  const int rowb = bm * 256 + wm + 4 * ((lane >> 5) & 1);
  if (EPI == 1) {
    #pragma unroll
    for (int ni = 0; ni < 2; ++ni) {
      const int col = colb + ni * 32;
      const float bb = bias[col];
      #pragma unroll
      for (int mi = 0; mi < 4; ++mi)
        #pragma unroll
        for (int r = 0; r < 16; ++r) {
          const int row = rowb + mi * 32 + (r & 3) + 8 * (r >> 2);
          float v = acc[mi][ni][r] + bb;
          v = v > 0.f ? v : 0.f;
          C[(long)row * N + col] = f2bu(v);
        }
    }
  } else {
    float bb[2], ww[2];
    #pragma unroll
    for (int ni = 0; ni < 2; ++ni) { bb[ni] = bias[colb + ni * 32]; ww[ni] = w3[colb + ni * 32]; }
    #pragma unroll
    for (int mi = 0; mi < 4; ++mi)
      #pragma unroll
      for (int r = 0; r < 16; ++r) {
        float s = 0.f;
        #pragma unroll
        for (int ni = 0; ni < 2; ++ni) {
          float v = acc[mi][ni][r] + bb[ni];
          v = v > 0.f ? v : 0.f;
          s += v * ww[ni];
        }
        s += __shfl_xor(s, 1, 64);
        s += __shfl_xor(s, 2, 64);
        s += __shfl_xor(s, 4, 64);
        s += __shfl_xor(s, 8, 64);
        s += __shfl_xor(s, 16, 64);
        if ((lane & 31) == 0)
          atomicAdd(&oacc[rowb + mi * 32 + (r & 3) + 8 * (r >> 2)], s);
      }
  }
#undef STAGE1
#undef RDA
#undef RDB
#undef MFMA8
}

// ---------------- segment ops ----------------
__global__ void k_detect(const int* __restrict__ seg, int n, int* __restrict__ flag) {
  if (blockIdx.x == 0 && threadIdx.x == 0) flag[0] = (seg[n - 1] == 0) ? 1 : 0;
}

__global__ void k_segsum(const float* __restrict__ oacc, const float* __restrict__ wacc,
                         const int* __restrict__ seg, const int* __restrict__ flag,
                         const float* __restrict__ ob3, const float* __restrict__ wb3,
                         float* __restrict__ osum, float* __restrict__ wsum, int n) {
  int i = blockIdx.x * blockDim.x + threadIdx.x;
  if (i >= n) return;
  int s = flag[0] ? seg[2 * i] : seg[i];
  atomicAdd(&osum[s], oacc[i] + ob3[0]);
  atomicAdd(&wsum[s], wacc[i] + wb3[0]);
}

__global__ void k_final(const float* __restrict__ oacc, const float* __restrict__ wacc,
                        const int* __restrict__ seg, const int* __restrict__ flag,
                        const float* __restrict__ ob3, const float* __restrict__ wb3,
                        const float* __restrict__ osum, const float* __restrict__ wsum,
                        float* __restrict__ out, int n) {
  int i = blockIdx.x * blockDim.x + threadIdx.x;
  if (i >= n) return;
  int s = flag[0] ? seg[2 * i] : seg[i];
  float o = oacc[i] + ob3[0];
  float ww = wacc[i] + wb3[0];
  out[i] = o - ww * (osum[s] / wsum[s]);
}

extern "C" void kernel_launch(void* const* d_in, const int* in_sizes, int n_in,
                              void* d_out, int out_size, void* d_ws, size_t ws_size,
                              hipStream_t stream) {
  constexpr int NA = 65536, D = 1024, H = 2048, M = 4096;
  const float* hidden = (const float*)d_in[0];
  const float* fW1 = (const float*)d_in[1];
  const float* fb1 = (const float*)d_in[2];
  const float* fW2 = (const float*)d_in[3];
  const float* fb2 = (const float*)d_in[4];
  const float* fW3 = (const float*)d_in[5];
  const float* fb3 = (const float*)d_in[6];
  const float* wW1 = (const float*)d_in[7];
  const float* wb1 = (const float*)d_in[8];
  const float* wW2 = (const float*)d_in[9];
  const float* wb2 = (const float*)d_in[10];
  const float* wW3 = (const float*)d_in[11];
  const float* wb3 = (const float*)d_in[12];
  const int* seg = (const int*)d_in[13];
  float* out = (float*)d_out;

  char* ws = (char*)d_ws;
  size_t off = 0;
  auto alloc = [&](size_t bytes) { char* p = ws + off; off += (bytes + 255) & ~(size_t)255; return p; };
  u16* hbf  = (u16*)alloc((size_t)NA * D * 2);
  u16* w1tf = (u16*)alloc((size_t)H * D * 2);
  u16* w1tw = (u16*)alloc((size_t)H * D * 2);
  u16* w2tf = (u16*)alloc((size_t)H * H * 2);
  u16* w2tw = (u16*)alloc((size_t)H * H * 2);
  u16* h1   = (u16*)alloc((size_t)NA * H * 2);
  float* oacc = (float*)alloc((size_t)NA * 4);
  float* wacc = (float*)alloc((size_t)NA * 4);
  float* osum = (float*)alloc((size_t)M * 4);
  float* wsum = (float*)alloc((size_t)M * 4);
  int* flag = (int*)alloc(256);

  // allow 128KB dynamic LDS (host-side attribute; capture-legal)
  hipFuncSetAttribute((const void*)k_gemm8<1>, hipFuncAttributeMaxDynamicSharedMemorySize, 131072);
  hipFuncSetAttribute((const void*)k_gemm8<2>, hipFuncAttributeMaxDynamicSharedMemorySize, 131072);

  // conversions
  k_f32_to_bf16<<<(int)((long)NA * D / 4 / 256), 256, 0, stream>>>(hidden, hbf, (long)NA * D / 4);
  dim3 tb(32, 8);
  k_transpose_bf16<<<dim3(H / 32, D / 32), tb, 0, stream>>>(fW1, w1tf, D, H);
  k_transpose_bf16<<<dim3(H / 32, D / 32), tb, 0, stream>>>(wW1, w1tw, D, H);
  k_transpose_bf16<<<dim3(H / 32, H / 32), tb, 0, stream>>>(fW2, w2tf, H, H);
  k_transpose_bf16<<<dim3(H / 32, H / 32), tb, 0, stream>>>(wW2, w2tw, H, H);

  hipMemsetAsync(oacc, 0, (size_t)((char*)flag - (char*)oacc), stream);
  k_detect<<<1, 64, 0, stream>>>(seg, NA, flag);

  const int nblk = (H / 256) * (NA / 256);   // 8 * 256 = 2048
  // ffn branch
  k_gemm8<1><<<nblk, 512, 131072, stream>>>(hbf, w1tf, h1, fb1, nullptr, nullptr, H, D);
  k_gemm8<2><<<nblk, 512, 131072, stream>>>(h1, w2tf, nullptr, fb2, fW3, oacc, H, H);
  // weight branch (reuses h1)
  k_gemm8<1><<<nblk, 512, 131072, stream>>>(hbf, w1tw, h1, wb1, nullptr, nullptr, H, D);
  k_gemm8<2><<<nblk, 512, 131072, stream>>>(h1, w2tw, nullptr, wb2, wW3, wacc, H, H);

  // segment ratio + final
  k_segsum<<<NA / 256, 256, 0, stream>>>(oacc, wacc, seg, flag, fb3, wb3, osum, wsum, NA);
  k_final<<<NA / 256, 256, 0, stream>>>(oacc, wacc, seg, flag, fb3, wb3, osum, wsum, out, NA);
}

// Round 7
// 1913.134 us; speedup vs baseline: 2.2904x; 2.2904x over previous
//
#include <hip/hip_runtime.h>
#include <hip/hip_bf16.h>

#define DEVINL __device__ __forceinline__

typedef __attribute__((ext_vector_type(8))) short s8v;   // 8 x bf16 bits
typedef __attribute__((ext_vector_type(4))) float f4v;   // MFMA accum

using bf16 = __hip_bfloat16;
typedef unsigned short u16;

DEVINL u16 f2bu(float f) {
  bf16 h = __float2bfloat16(f);  // RNE
  return *reinterpret_cast<u16*>(&h);
}

DEVINL void gload16(const void* g, void* l) {
  // async global->LDS, 16B/lane; LDS dest = wave-uniform base + lane*16
  __builtin_amdgcn_global_load_lds((const __attribute__((address_space(1))) void*)g,
                                   (__attribute__((address_space(3))) void*)l, 16, 0, 0);
}

#define BAR()    __builtin_amdgcn_s_barrier()
#define LGKM(n)  asm volatile("s_waitcnt lgkmcnt(" #n ")" ::: "memory")
#define VM(n)    asm volatile("s_waitcnt vmcnt(" #n ")" ::: "memory")

// ---------------- conversion kernels ----------------
__global__ void k_f32_to_bf16(const float* __restrict__ x, u16* __restrict__ y, long n4) {
  long i = (long)blockIdx.x * blockDim.x + threadIdx.x;
  if (i >= n4) return;
  float4 v = ((const float4*)x)[i];
  ushort4 o;
  o.x = f2bu(v.x); o.y = f2bu(v.y); o.z = f2bu(v.z); o.w = f2bu(v.w);
  ((ushort4*)y)[i] = o;
}

// W [rows][cols] fp32 -> Wt [cols][rows] bf16
__global__ void k_transpose_bf16(const float* __restrict__ W, u16* __restrict__ Wt,
                                 int rows, int cols) {
  __shared__ float tile[32][33];
  const int tx = threadIdx.x, ty = threadIdx.y;
  const int c0 = blockIdx.x * 32, r0 = blockIdx.y * 32;
  #pragma unroll
  for (int i = ty; i < 32; i += 8)
    tile[i][tx] = W[(long)(r0 + i) * cols + (c0 + tx)];
  __syncthreads();
  #pragma unroll
  for (int i = ty; i < 32; i += 8)
    Wt[(long)(c0 + i) * rows + (r0 + tx)] = f2bu(tile[tx][i]);
}

// ---------------- 256x256 GEMM, R4 schedule + compile-time buffers -----------
// 8 waves (2M x 4N), BK=64, LDS 128KB = 2 dbuf x {A[2ks][256][32], B[2ks][256][32]}
// Swizzle: 16B slot j of row r holds k-chunk j ^ ((r>>1)&3) (0-conflict b128).
// R4 fragment pipeline (counted LGKM), t-loop unrolled x2 so buffer parity is
// compile-time: all ds_reads fold to base_reg+imm, stage addrs to runptr+imm.
// Drains (hand-audited FIFO, steady + tail): VM(6)@P2, VM(8)@P4; tail 4/0.
// EPI=1: C = bf16(relu(acc+bias[col]));  EPI=2: oacc[row] += sum relu(..)*w3
extern __shared__ char smem[];

template<int EPI, int NT>
__global__ __launch_bounds__(512, 2)
void k_gemm8(const u16* __restrict__ A, const u16* __restrict__ Bt,
             u16* __restrict__ C, const float* __restrict__ bias,
             const float* __restrict__ w3, float* __restrict__ oacc,
             int N, int K) {
  const int tid = threadIdx.x;
  const int w = tid >> 6, lane = tid & 63;
  // XCD-aware bijective swizzle (gridDim.x % 8 == 0: 2048 blocks)
  const int id = blockIdx.x;
  const int cpx = gridDim.x >> 3;
  const int sw = (id & 7) * cpx + (id >> 3);
  const int bn = sw & 7, bm = sw >> 3;          // N/256 == 8 for all our calls

  const int wm = (w >> 2) * 128, wn = (w & 3) * 64;

  f4v acc[8][4];
  #pragma unroll
  for (int i = 0; i < 8; ++i)
    #pragma unroll
    for (int jj = 0; jj < 4; ++jj)
      #pragma unroll
      for (int r = 0; r < 4; ++r) acc[i][jj][r] = 0.f;

  // ---- staging bases (pre-swizzled global source, linear LDS dest) ----
  const int rowl = tid >> 2;                           // 0..127 row within chunk
  const int jsw = (tid & 3) ^ ((rowl >> 1) & 3);       // swizzled k-chunk
  const u16* gA = A + (long)(bm * 256 + rowl) * K + jsw * 8;   // running ptr
  const u16* gB = Bt + (long)(bn * 256 + rowl) * K + jsw * 8;  // running ptr
  const long cstr = (long)128 * K;                     // chunk-1 global row offset
  const uint wb = (uint)w * 1024u;                     // wave slice within 8KB chunk

  // ---- ds_read bases (swizzled) ----
  const uint swz = ((uint)((lane >> 4) ^ ((lane >> 1) & 3))) * 16u;
  const uint aoff = (uint)(wm + (lane & 15)) * 64u + swz;            // A region
  const uint boff = (uint)(wn + (lane & 15)) * 64u + swz + 32768u;   // B region

#define STAGE_A(pp, ks, rel) do { \
    const u16* g_ = gA + (rel) * 64 + (ks) * 32; \
    char* l_ = smem + (uint)(pp) * 65536u + (uint)(ks) * 16384u + wb; \
    gload16(g_, l_); gload16(g_ + cstr, l_ + 8192); } while (0)
#define STAGE_B(pp, ks, rel) do { \
    const u16* g_ = gB + (rel) * 64 + (ks) * 32; \
    char* l_ = smem + (uint)(pp) * 65536u + 32768u + (uint)(ks) * 16384u + wb; \
    gload16(g_, l_); gload16(g_ + cstr, l_ + 8192); } while (0)

#define RD_A(dst, pbc, ksb) do { \
    _Pragma("unroll") \
    for (int mi_ = 0; mi_ < 8; ++mi_) \
      dst[mi_] = *(const s8v*)(smem + (pbc) + (ksb) + aoff + (uint)mi_ * 1024u); } while (0)
#define RD_B(dst, pbc, ksb, c0) do { \
    dst[0] = *(const s8v*)(smem + (pbc) + (ksb) + boff + (uint)(c0) * 1024u); \
    dst[1] = *(const s8v*)(smem + (pbc) + (ksb) + boff + (uint)((c0) + 1) * 1024u); } while (0)

#define MFMA8(A_, B_, c0i, c1i) do { \
    __builtin_amdgcn_s_setprio(1); \
    _Pragma("unroll") \
    for (int mi_ = 0; mi_ < 8; ++mi_) { \
      acc[mi_][c0i] = __builtin_amdgcn_mfma_f32_16x16x32_bf16(A_[mi_], B_[0], acc[mi_][c0i], 0, 0, 0); \
      acc[mi_][c1i] = __builtin_amdgcn_mfma_f32_16x16x32_bf16(A_[mi_], B_[1], acc[mi_][c1i], 0, 0, 0); \
    } \
    __builtin_amdgcn_s_setprio(0); } while (0)

// One K-tile, R4 phase schedule. P = buffer parity (compile-time literal).
// REL1/REL2 = global tile offsets (vs running ptr) for t+1 / t+2 staging.
// S1 = stage (t+1).k1, S2 = stage (t+2).k0, R1 = issue next-tile P1 reads.
#define TILE(P, REL1, REL2, S1, S2, R1) do { \
    /* P1: MFMA(k0,c01); prefetch b23(k0) issued last phase? no: here */ \
    RD_B(b23, (P) * 65536u, 0u, 2); \
    if (S1) STAGE_A(1 - (P), 1, REL1); \
    BAR(); LGKM(2); \
    MFMA8(a0, b01, 0, 1); \
    /* P2: MFMA(k0,c23); prefetch k1 frags */ \
    if (S1) { VM(6); } else { VM(0); } \
    BAR(); \
    RD_A(a1, (P) * 65536u, 16384u); RD_B(b01, (P) * 65536u, 16384u, 0); \
    if (S1) STAGE_B(1 - (P), 1, REL1); \
    LGKM(10); \
    MFMA8(a0, b23, 2, 3); \
    /* P3: MFMA(k1,c01); prefetch b23(k1) */ \
    RD_B(b23, (P) * 65536u, 16384u, 2); \
    if (S2) STAGE_A((P), 0, REL2); \
    BAR(); LGKM(2); \
    MFMA8(a1, b01, 0, 1); \
    /* P4: MFMA(k1,c23); prefetch next-tile k0 frags */ \
    if (S2) { \
      STAGE_B((P), 0, REL2); \
      VM(8); BAR(); \
      RD_A(a0, (1 - (P)) * 65536u, 0u); RD_B(b01, (1 - (P)) * 65536u, 0u, 0); \
      LGKM(10); \
    } else if (R1) { \
      VM(4); BAR(); \
      RD_A(a0, (1 - (P)) * 65536u, 0u); RD_B(b01, (1 - (P)) * 65536u, 0u, 0); \
      LGKM(10); \
    } else { \
      BAR(); LGKM(0); \
    } \
    MFMA8(a1, b23, 2, 3); \
  } while (0)

  s8v a0[8], a1[8], b01[2], b23[2];

  // ---- prologue: stage t0 fully + t1.k0; drain t0.k0; issue t0 P1 reads ----
  STAGE_A(0, 0, 0); STAGE_B(0, 0, 0); STAGE_A(0, 1, 0); STAGE_B(0, 1, 0);
  STAGE_A(1, 0, 1); STAGE_B(1, 0, 1);
  VM(8); BAR();
  RD_A(a0, 0u, 0u); RD_B(b01, 0u, 0u, 0);   // 10 reads in flight for P1

  // ---- main pairs (t, t+1), buffer parity compile-time ----
  #pragma unroll 1
  for (int tp = 0; tp < NT / 2 - 1; ++tp) {
    TILE(0, 1, 2, 1, 1, 1);
    TILE(1, 2, 3, 1, 1, 1);
    gA += 128; gB += 128;
  }
  // ---- tail pair: t = NT-2 (stage only (NT-1).k1), t = NT-1 (no stages) ----
  TILE(0, 1, 2, 1, 0, 1);
  TILE(1, 2, 3, 0, 0, 0);

  // ---- epilogue (C/D: col = lane&15, row = (lane>>4)*4 + reg) ----
  const int crow = bm * 256 + wm + ((lane >> 4) << 2);
  const int ccol = bn * 256 + wn + (lane & 15);
  if (EPI == 1) {
    #pragma unroll
    for (int jj = 0; jj < 4; ++jj) {
      const float bb = bias[ccol + jj * 16];
      #pragma unroll
      for (int mi = 0; mi < 8; ++mi)
        #pragma unroll
        for (int r = 0; r < 4; ++r) {
          float v = acc[mi][jj][r] + bb;
          v = v > 0.f ? v : 0.f;
          C[(long)(crow + mi * 16 + r) * N + ccol + jj * 16] = f2bu(v);
        }
    }
  } else {
    float bb[4], ww[4];
    #pragma unroll
    for (int jj = 0; jj < 4; ++jj) { bb[jj] = bias[ccol + jj * 16]; ww[jj] = w3[ccol + jj * 16]; }
    #pragma unroll
    for (int mi = 0; mi < 8; ++mi)
      #pragma unroll
      for (int r = 0; r < 4; ++r) {
        float s = 0.f;
        #pragma unroll
        for (int jj = 0; jj < 4; ++jj) {
          float v = acc[mi][jj][r] + bb[jj];
          v = v > 0.f ? v : 0.f;
          s += v * ww[jj];
        }
        s += __shfl_xor(s, 1, 64);
        s += __shfl_xor(s, 2, 64);
        s += __shfl_xor(s, 4, 64);
        s += __shfl_xor(s, 8, 64);
        if ((lane & 15) == 0) atomicAdd(&oacc[crow + mi * 16 + r], s);
      }
  }
#undef STAGE_A
#undef STAGE_B
#undef RD_A
#undef RD_B
#undef MFMA8
#undef TILE
}

// ---------------- segment ops ----------------
__global__ void k_detect(const int* __restrict__ seg, int n, int* __restrict__ flag) {
  if (blockIdx.x == 0 && threadIdx.x == 0) flag[0] = (seg[n - 1] == 0) ? 1 : 0;
}

__global__ void k_segsum(const float* __restrict__ oacc, const float* __restrict__ wacc,
                         const int* __restrict__ seg, const int* __restrict__ flag,
                         const float* __restrict__ ob3, const float* __restrict__ wb3,
                         float* __restrict__ osum, float* __restrict__ wsum, int n) {
  int i = blockIdx.x * blockDim.x + threadIdx.x;
  if (i >= n) return;
  int s = flag[0] ? seg[2 * i] : seg[i];
  atomicAdd(&osum[s], oacc[i] + ob3[0]);
  atomicAdd(&wsum[s], wacc[i] + wb3[0]);
}

__global__ void k_final(const float* __restrict__ oacc, const float* __restrict__ wacc,
                        const int* __restrict__ seg, const int* __restrict__ flag,
                        const float* __restrict__ ob3, const float* __restrict__ wb3,
                        const float* __restrict__ osum, const float* __restrict__ wsum,
                        float* __restrict__ out, int n) {
  int i = blockIdx.x * blockDim.x + threadIdx.x;
  if (i >= n) return;
  int s = flag[0] ? seg[2 * i] : seg[i];
  float o = oacc[i] + ob3[0];
  float ww = wacc[i] + wb3[0];
  out[i] = o - ww * (osum[s] / wsum[s]);
}

extern "C" void kernel_launch(void* const* d_in, const int* in_sizes, int n_in,
                              void* d_out, int out_size, void* d_ws, size_t ws_size,
                              hipStream_t stream) {
  constexpr int NA = 65536, D = 1024, H = 2048, M = 4096;
  const float* hidden = (const float*)d_in[0];
  const float* fW1 = (const float*)d_in[1];
  const float* fb1 = (const float*)d_in[2];
  const float* fW2 = (const float*)d_in[3];
  const float* fb2 = (const float*)d_in[4];
  const float* fW3 = (const float*)d_in[5];
  const float* fb3 = (const float*)d_in[6];
  const float* wW1 = (const float*)d_in[7];
  const float* wb1 = (const float*)d_in[8];
  const float* wW2 = (const float*)d_in[9];
  const float* wb2 = (const float*)d_in[10];
  const float* wW3 = (const float*)d_in[11];
  const float* wb3 = (const float*)d_in[12];
  const int* seg = (const int*)d_in[13];
  float* out = (float*)d_out;

  char* ws = (char*)d_ws;
  size_t off = 0;
  auto alloc = [&](size_t bytes) { char* p = ws + off; off += (bytes + 255) & ~(size_t)255; return p; };
  u16* hbf  = (u16*)alloc((size_t)NA * D * 2);
  u16* w1tf = (u16*)alloc((size_t)H * D * 2);
  u16* w1tw = (u16*)alloc((size_t)H * D * 2);
  u16* w2tf = (u16*)alloc((size_t)H * H * 2);
  u16* w2tw = (u16*)alloc((size_t)H * H * 2);
  u16* h1   = (u16*)alloc((size_t)NA * H * 2);
  float* oacc = (float*)alloc((size_t)NA * 4);
  float* wacc = (float*)alloc((size_t)NA * 4);
  float* osum = (float*)alloc((size_t)M * 4);
  float* wsum = (float*)alloc((size_t)M * 4);
  int* flag = (int*)alloc(256);

  // allow 128KB dynamic LDS (host-side attribute; capture-legal)
  hipFuncSetAttribute((const void*)k_gemm8<1, 16>, hipFuncAttributeMaxDynamicSharedMemorySize, 131072);
  hipFuncSetAttribute((const void*)k_gemm8<2, 32>, hipFuncAttributeMaxDynamicSharedMemorySize, 131072);

  // conversions
  k_f32_to_bf16<<<(int)((long)NA * D / 4 / 256), 256, 0, stream>>>(hidden, hbf, (long)NA * D / 4);
  dim3 tb(32, 8);
  k_transpose_bf16<<<dim3(H / 32, D / 32), tb, 0, stream>>>(fW1, w1tf, D, H);
  k_transpose_bf16<<<dim3(H / 32, D / 32), tb, 0, stream>>>(wW1, w1tw, D, H);
  k_transpose_bf16<<<dim3(H / 32, H / 32), tb, 0, stream>>>(fW2, w2tf, H, H);
  k_transpose_bf16<<<dim3(H / 32, H / 32), tb, 0, stream>>>(wW2, w2tw, H, H);

  hipMemsetAsync(oacc, 0, (size_t)((char*)flag - (char*)oacc), stream);
  k_detect<<<1, 64, 0, stream>>>(seg, NA, flag);

  const int nblk = (H / 256) * (NA / 256);   // 8 * 256 = 2048
  // ffn branch
  k_gemm8<1, 16><<<nblk, 512, 131072, stream>>>(hbf, w1tf, h1, fb1, nullptr, nullptr, H, D);
  k_gemm8<2, 32><<<nblk, 512, 131072, stream>>>(h1, w2tf, nullptr, fb2, fW3, oacc, H, H);
  // weight branch (reuses h1)
  k_gemm8<1, 16><<<nblk, 512, 131072, stream>>>(hbf, w1tw, h1, wb1, nullptr, nullptr, H, D);
  k_gemm8<2, 32><<<nblk, 512, 131072, stream>>>(h1, w2tw, nullptr, wb2, wW3, wacc, H, H);

  // segment ratio + final
  k_segsum<<<NA / 256, 256, 0, stream>>>(oacc, wacc, seg, flag, fb3, wb3, osum, wsum, NA);
  k_final<<<NA / 256, 256, 0, stream>>>(oacc, wacc, seg, flag, fb3, wb3, osum, wsum, out, NA);
}